// Round 14
// baseline (81.188 us; speedup 1.0000x reference)
//
#include <hip/hip_runtime.h>
#include <hip/hip_bf16.h>
#include <stdint.h>

#define BATCH 8192
#define DIM   1024
#define BM 64
#define BN 64
#define BK 64
#define STEPS 16                 // DIM / BK
#define BUF 24576                // Xs f32 16K + Bs bf16 8K

typedef __attribute__((ext_vector_type(4))) float f32x4;
typedef __attribute__((ext_vector_type(8))) short bf16x8;
typedef __attribute__((ext_vector_type(8))) unsigned short u16x8;

#define AS1(p) ((const __attribute__((address_space(1))) void*)(p))
#define AS3(p) ((__attribute__((address_space(3))) void*)(p))

__device__ __forceinline__ unsigned short f2bf(float f) {
    union { __hip_bfloat16 h; unsigned short u; } v;
    v.h = __hip_bfloat16(f);
    return v.u;
}
__device__ __forceinline__ float sigma_f(float x) {
    float x2 = x * x;
    return x2 * __builtin_amdgcn_rcpf(1.0f + x2);
}

// ---------------------------------------------------------------------------
// K1: A (f32 [D][D]) -> bf16 ws.  512 blocks, 8 elems/thread.
// ---------------------------------------------------------------------------
__global__ __launch_bounds__(256) void convA_kernel(
    const float* __restrict__ A, unsigned short* __restrict__ Ab)
{
    const int i = blockIdx.x * 256 + threadIdx.x;   // u16x8 index
    f32x4 v0 = ((const f32x4*)A)[i * 2];
    f32x4 v1 = ((const f32x4*)A)[i * 2 + 1];
    u16x8 ab;
#pragma unroll
    for (int e = 0; e < 4; ++e) {
        ab[e]     = f2bf(v0[e]);
        ab[e + 4] = f2bf(v1[e]);
    }
    ((u16x8*)Ab)[i] = ab;
}

// ---------------------------------------------------------------------------
// K2: fused GEMM, 64x64 tile, x staged AS F32 via glds (counted-vmcnt
//   3-buffer pipeline, R13-proven); sigma computed IN-REGISTER at
//   fragment-read time (ds_read f32x4 pair -> sigma -> cvt_pk -> bf16x8).
//   2048 blocks (2/CU), 4 waves (2x2: 32x32/wave, acc[2][2]).
//   LDS 72K = 3 x {Xs f32 16K | Bs bf16 8K}; epilogue C f32[64][64] reuses.
//   Per step: vmcnt(6) -> raw s_barrier -> issue stage(t+2) -> frag reads
//   (+sigma cvt) + 8 MFMA. Epilogue recomputes base, writes out0/1/2.
// ---------------------------------------------------------------------------
__global__ __launch_bounds__(256, 2) void gemm_kernel(
    const float* __restrict__ x, const float* __restrict__ ex,
    const float* __restrict__ W, const float* __restrict__ tgt,
    const unsigned short* __restrict__ Abf,
    float* __restrict__ out0, float* __restrict__ out1,
    float* __restrict__ out2)
{
    __shared__ __align__(16) char lds[3 * BUF];

    // ---- block mapping: 16 consecutive bns per bm; 16 bms per XCD
    const int b     = blockIdx.x;
    const int xcd   = b & 7;
    const int local = b >> 3;                    // 0..255
    const int bm    = xcd * 16 + (local >> 4);   // 0..127
    const int bn    = local & 15;                // 0..15

    const int tid  = threadIdx.x;
    const int lane = tid & 63;
    const int wid  = tid >> 6;                   // 0..3
    const int wr   = wid >> 1, wc = wid & 1;
    const int l15  = lane & 15;

    const char* xB = (const char*)x + (size_t)(bm * BM) * (DIM * 4);

    // ---- B staging source (R13 pattern, 64-row tile, 2 insts/wave)
    const int swzB = (((lane & 7) ^ (lane >> 3)) << 4);
    const char* gB = (const char*)Abf +
        ((size_t)(bn * BN + wid * 16 + (lane >> 3)) * DIM) * 2 + swzB;

    // ---- X staging source rows (4 insts/wave, 4 rows each)
    // row_j = wid*16 + j*4 + (lane>>4); src col = ((l&15)*16) ^ ((row&7)<<4)
    const int xrow_base = wid * 16 + (lane >> 4);

    // ---- fragment read constants
    const int rd_sw = (lane & 7) << 4;
    const int cb0   = (lane >> 4) << 4;          // bf16 B frag k-byte
    const int kbA   = (lane >> 4) << 5;          // f32 A frag k-byte

    f32x4 acc[2][2];
#pragma unroll
    for (int mi = 0; mi < 2; ++mi)
#pragma unroll
        for (int ni = 0; ni < 2; ++ni)
            acc[mi][ni] = f32x4{0.f, 0.f, 0.f, 0.f};

    auto stage = [&](int t) {                    // 6 glds per wave
        char* Xs = lds + (t % 3) * BUF;
        char* Bs = Xs + 16384;
#pragma unroll
        for (int j = 0; j < 4; ++j) {
            const int row = xrow_base + j * 4;
            __builtin_amdgcn_global_load_lds(
                AS1(xB + (size_t)row * (DIM * 4) + (size_t)t * 256 +
                    (((l15) * 16) ^ ((row & 7) << 4))),
                AS3(Xs + (wid * 16 + j * 4) * 256), 16, 0, 0);
        }
#pragma unroll
        for (int j = 0; j < 2; ++j)
            __builtin_amdgcn_global_load_lds(
                AS1(gB + (size_t)j * (8 * DIM * 2) + (size_t)t * 128),
                AS3(Bs + (wid * 16 + j * 8) * 128), 16, 0, 0);
    };

    // ---- prologue: two stages in flight
    stage(0);
    stage(1);

    // ---- main loop: counted vmcnt + raw barrier (R13-proven)
    for (int t = 0; t < STEPS; ++t) {
        __builtin_amdgcn_sched_barrier(0);
        if (t < STEPS - 1) asm volatile("s_waitcnt vmcnt(6)" ::: "memory");
        else               asm volatile("s_waitcnt vmcnt(0)" ::: "memory");
        __builtin_amdgcn_sched_barrier(0);
        __builtin_amdgcn_s_barrier();
        __builtin_amdgcn_sched_barrier(0);
        if (t + 2 < STEPS) stage(t + 2);
        __builtin_amdgcn_sched_barrier(0);

        const char* Xs_ = lds + (t % 3) * BUF;
        const char* Bs_ = Xs_ + 16384;
#pragma unroll
        for (int kk = 0; kk < 2; ++kk) {
            bf16x8 af[2], bfr[2];
#pragma unroll
            for (int mi = 0; mi < 2; ++mi) {
                const int arow = wr * 32 + mi * 16 + l15;
                const int kb   = kk * 128 + kbA;
                f32x4 f0 = *(const f32x4*)(Xs_ + arow * 256 + (kb ^ rd_sw));
                f32x4 f1 = *(const f32x4*)(Xs_ + arow * 256 + ((kb + 16) ^ rd_sw));
                union { u16x8 u; bf16x8 bv; } cvu;
#pragma unroll
                for (int i = 0; i < 4; ++i) {
                    cvu.u[i]     = f2bf(sigma_f(f0[i]));
                    cvu.u[i + 4] = f2bf(sigma_f(f1[i]));
                }
                af[mi] = cvu.bv;
            }
#pragma unroll
            for (int ni = 0; ni < 2; ++ni)
                bfr[ni] = *(const bf16x8*)(Bs_ + (wc * 32 + ni * 16 + l15) * 128 +
                                           ((cb0 + kk * 64) ^ rd_sw));
#pragma unroll
            for (int mi = 0; mi < 2; ++mi)
#pragma unroll
                for (int ni = 0; ni < 2; ++ni)
                    acc[mi][ni] = __builtin_amdgcn_mfma_f32_16x16x32_bf16(
                        af[mi], bfr[ni], acc[mi][ni], 0, 0, 0);
        }
    }

    // ---- epilogue: C -> LDS f32[64][64] linear, then streaming pass
    __syncthreads();
#pragma unroll
    for (int mi = 0; mi < 2; ++mi)
#pragma unroll
        for (int ni = 0; ni < 2; ++ni) {
            const int row_ = wr * 32 + mi * 16 + ((lane >> 4) << 2);
            const int colb = (wc * 32 + ni * 16 + l15) * 4;
#pragma unroll
            for (int r = 0; r < 4; ++r)
                *(float*)(lds + (row_ + r) * 256 + colb) = acc[mi][ni][r];
        }
    __syncthreads();

#pragma unroll
    for (int p = 0; p < 4; ++p) {
        const int ci  = p * 256 + tid;           // 0..1023
        const int row = ci >> 4;                 // 0..63
        const int cv  = ci & 15;                 // 0..15
        f32x4 c = *(const f32x4*)(lds + row * 256 + cv * 16);
        const size_t v4 = (size_t)(bm * BM + row) * (DIM / 4) + bn * 16 + cv;
        f32x4 xv = ((const f32x4*)x)[v4];
        f32x4 ev = ((const f32x4*)ex)[v4];
        f32x4 wv = ((const f32x4*)W)[v4];
        f32x4 tv = ((const f32x4*)tgt)[bn * 16 + cv];
        f32x4 o0;
#pragma unroll
        for (int e = 0; e < 4; ++e) {
            float xi = xv[e], ti = tv[e];
            float ba = ti * ti * __builtin_amdgcn_rcpf(1.0f + ti * ti);
            float u  = -(wv[e] * (xi + ev[e] - ti)) * ba;
            float s  = sigma_f(xi);
            o0[e] = -xi + u * s + c[e];
        }
        ((f32x4*)out0)[v4] = o0;
        ((f32x4*)out1)[v4] = -o0;
        ((f32x4*)out2)[v4] = f32x4{0.f, 0.f, 0.f, 0.f};
    }
}

// ---------------------------------------------------------------------------
extern "C" void kernel_launch(void* const* d_in, const int* in_sizes, int n_in,
                              void* d_out, int out_size, void* d_ws, size_t ws_size,
                              hipStream_t stream)
{
    const float* x   = (const float*)d_in[0];
    const float* ex  = (const float*)d_in[1];
    const float* W   = (const float*)d_in[2];
    const float* A   = (const float*)d_in[3];
    const float* tgt = (const float*)d_in[4];

    float* out0 = (float*)d_out;
    float* out1 = out0 + (size_t)BATCH * DIM;
    float* out2 = out1 + (size_t)BATCH * DIM;

    unsigned short* Abf = (unsigned short*)d_ws;   // 2 MiB

    convA_kernel<<<DIM * DIM / 8 / 256, 256, 0, stream>>>(A, Abf);
    gemm_kernel<<<(BATCH / BM) * (DIM / BN), 256, 0, stream>>>(
        x, ex, W, tgt, Abf, out0, out1, out2);
}

// Round 15
// 57.341 us; speedup vs baseline: 1.4159x; 1.4159x over previous
//
#include <hip/hip_runtime.h>
#include <hip/hip_bf16.h>
#include <stdint.h>

#define BATCH 8192
#define DIM   1024
#define BM 128
#define BN 64
#define BK 64
#define STEPS 16                 // DIM / BK
#define BUF 24576                // A 16K + B 8K per stage buffer

typedef __attribute__((ext_vector_type(4))) float f32x4;
typedef __attribute__((ext_vector_type(8))) short bf16x8;
typedef __attribute__((ext_vector_type(8))) unsigned short u16x8;

#define AS1(p) ((const __attribute__((address_space(1))) void*)(p))
#define AS3(p) ((__attribute__((address_space(3))) void*)(p))

__device__ __forceinline__ unsigned short f2bf(float f) {
    union { __hip_bfloat16 h; unsigned short u; } v;
    v.h = __hip_bfloat16(f);
    return v.u;
}
__device__ __forceinline__ float sigma_f(float x) {
    float x2 = x * x;
    return x2 * __builtin_amdgcn_rcpf(1.0f + x2);
}

// ---------------------------------------------------------------------------
// K1: sigma(x) -> bf16 ws + out2 zeros (4096 blocks) | A -> bf16 (512 blocks)
// ---------------------------------------------------------------------------
__global__ __launch_bounds__(256) void prep_kernel(
    const float* __restrict__ x, const float* __restrict__ A,
    unsigned short* __restrict__ sigb, unsigned short* __restrict__ Abf,
    float* __restrict__ out2)
{
    const int i = blockIdx.x * 256 + threadIdx.x;
    if (i < BATCH * DIM / 8) {
        f32x4 v0 = ((const f32x4*)x)[i * 2];
        f32x4 v1 = ((const f32x4*)x)[i * 2 + 1];
        u16x8 sb;
#pragma unroll
        for (int e = 0; e < 4; ++e) {
            sb[e]     = f2bf(sigma_f(v0[e]));
            sb[e + 4] = f2bf(sigma_f(v1[e]));
        }
        ((u16x8*)sigb)[i] = sb;
        ((f32x4*)out2)[i * 2]     = f32x4{0.f, 0.f, 0.f, 0.f};
        ((f32x4*)out2)[i * 2 + 1] = f32x4{0.f, 0.f, 0.f, 0.f};
    } else {
        const int j = i - BATCH * DIM / 8;       // < 131072
        f32x4 v0 = ((const f32x4*)A)[j * 2];
        f32x4 v1 = ((const f32x4*)A)[j * 2 + 1];
        u16x8 ab;
#pragma unroll
        for (int e = 0; e < 4; ++e) {
            ab[e]     = f2bf(v0[e]);
            ab[e + 4] = f2bf(v1[e]);
        }
        ((u16x8*)Abf)[j] = ab;
    }
}

// ---------------------------------------------------------------------------
// K2: GEMM 128x64 tile, R13-proven glds/counted-vmcnt/raw-barrier pipeline,
//   now 512 threads (8 waves, wave grid 4x2: 32x32/wave, acc[2][2]) for
//   16 waves/CU (2 blocks x 8 waves): doubles latency-hiding TLP for both
//   the K-loop and the streaming epilogue.
//   LDS 72 KiB = 3 stage buffers x {A 16K | B 8K}; C-dump reuses [0,32K).
//   Per step: vmcnt(3) -> raw s_barrier -> issue stage(t+2) (3 glds/wave)
//   -> ds_read + 8 MFMA/wave. Epilogue recomputes base, writes out0/out1.
// ---------------------------------------------------------------------------
__global__ __launch_bounds__(512, 4) void gemm_kernel(
    const float* __restrict__ x, const float* __restrict__ ex,
    const float* __restrict__ W, const float* __restrict__ tgt,
    const unsigned short* __restrict__ sigb,
    const unsigned short* __restrict__ Abf,
    float* __restrict__ out0, float* __restrict__ out1)
{
    __shared__ __align__(16) char lds[3 * BUF];

    // ---- block mapping: same-bm blocks share an XCD (sigb/x L2 reuse)
    const int b     = blockIdx.x;
    const int xcd   = b & 7;
    const int local = b >> 3;                    // 0..127
    const int bm    = xcd * 8 + (local >> 4);    // 0..63
    const int bn    = local & 15;                // 0..15

    const int tid  = threadIdx.x;
    const int lane = tid & 63;
    const int wid  = tid >> 6;                   // 0..7
    const int wr   = wid >> 1, wc = wid & 1;     // 4x2 wave grid
    const int l15  = lane & 15;

    // ---- staging source addresses (pre-swizzled source, linear LDS dest)
    const int swz = (((lane & 7) ^ (lane >> 3)) << 4);
    const char* gS = (const char*)sigb +
        ((size_t)(bm * BM + wid * 8 + (lane >> 3)) * DIM) * 2 + swz;
    const char* gB = (const char*)Abf +
        ((size_t)(bn * BN + wid * 8 + (lane >> 3)) * DIM) * 2 + swz;

    // ---- fragment read constants (R13-verified)
    const int rd_sw = (lane & 7) << 4;
    const int cb0   = (lane >> 4) << 4;

    f32x4 acc[2][2];
#pragma unroll
    for (int mi = 0; mi < 2; ++mi)
#pragma unroll
        for (int ni = 0; ni < 2; ++ni)
            acc[mi][ni] = f32x4{0.f, 0.f, 0.f, 0.f};

    auto stage = [&](int t) {                    // 3 glds per wave
        char* As = lds + (t % 3) * BUF;
        char* Bs = As + 16384;
        const size_t ko = (size_t)t * (BK * 2);
#pragma unroll
        for (int j = 0; j < 2; ++j)
            __builtin_amdgcn_global_load_lds(
                AS1(gS + (size_t)j * (64 * DIM * 2) + ko),
                AS3(As + (wid * 8 + j * 64) * 128), 16, 0, 0);
        __builtin_amdgcn_global_load_lds(
            AS1(gB + ko), AS3(Bs + wid * 8 * 128), 16, 0, 0);
    };

    // ---- prologue: two stages in flight
    stage(0);
    stage(1);

    // ---- main loop: one counted wait + one raw barrier per step
    for (int t = 0; t < STEPS; ++t) {
        __builtin_amdgcn_sched_barrier(0);
        if (t < STEPS - 1) asm volatile("s_waitcnt vmcnt(3)" ::: "memory");
        else               asm volatile("s_waitcnt vmcnt(0)" ::: "memory");
        __builtin_amdgcn_sched_barrier(0);
        __builtin_amdgcn_s_barrier();
        __builtin_amdgcn_sched_barrier(0);
        if (t + 2 < STEPS) stage(t + 2);
        __builtin_amdgcn_sched_barrier(0);

        const char* As_ = lds + (t % 3) * BUF;
        const char* Bs_ = As_ + 16384;
#pragma unroll
        for (int kk = 0; kk < 2; ++kk) {
            bf16x8 af[2], bfr[2];
#pragma unroll
            for (int mi = 0; mi < 2; ++mi)
                af[mi] = *(const bf16x8*)(As_ + (wr * 32 + mi * 16 + l15) * 128 +
                                          ((cb0 + kk * 64) ^ rd_sw));
#pragma unroll
            for (int ni = 0; ni < 2; ++ni)
                bfr[ni] = *(const bf16x8*)(Bs_ + (wc * 32 + ni * 16 + l15) * 128 +
                                           ((cb0 + kk * 64) ^ rd_sw));
#pragma unroll
            for (int mi = 0; mi < 2; ++mi)
#pragma unroll
                for (int ni = 0; ni < 2; ++ni)
                    acc[mi][ni] = __builtin_amdgcn_mfma_f32_16x16x32_bf16(
                        af[mi], bfr[ni], acc[mi][ni], 0, 0, 0);
        }
    }

    // ---- epilogue: C -> LDS f32[128][64] (linear), then streaming pass
    __syncthreads();
#pragma unroll
    for (int mi = 0; mi < 2; ++mi)
#pragma unroll
        for (int ni = 0; ni < 2; ++ni) {
            const int row_ = wr * 32 + mi * 16 + ((lane >> 4) << 2);
            const int colb = (wc * 32 + ni * 16 + l15) * 4;
#pragma unroll
            for (int r = 0; r < 4; ++r)
                *(float*)(lds + (row_ + r) * 256 + colb) = acc[mi][ni][r];
        }
    __syncthreads();

#pragma unroll
    for (int p = 0; p < 4; ++p) {
        const int ci  = p * 512 + tid;           // 0..2047
        const int row = ci >> 4;                 // 0..127
        const int cv  = ci & 15;                 // 0..15
        f32x4 c = *(const f32x4*)(lds + row * 256 + cv * 16);
        const size_t v4 = (size_t)(bm * BM + row) * (DIM / 4) + bn * 16 + cv;
        f32x4 xv = ((const f32x4*)x)[v4];
        f32x4 ev = ((const f32x4*)ex)[v4];
        f32x4 wv = ((const f32x4*)W)[v4];
        f32x4 tv = ((const f32x4*)tgt)[bn * 16 + cv];
        f32x4 o0;
#pragma unroll
        for (int e = 0; e < 4; ++e) {
            float xi = xv[e], ti = tv[e];
            float ba = ti * ti * __builtin_amdgcn_rcpf(1.0f + ti * ti);
            float u  = -(wv[e] * (xi + ev[e] - ti)) * ba;
            float s  = sigma_f(xi);
            o0[e] = -xi + u * s + c[e];
        }
        ((f32x4*)out0)[v4] = o0;
        ((f32x4*)out1)[v4] = -o0;
    }
}

// ---------------------------------------------------------------------------
extern "C" void kernel_launch(void* const* d_in, const int* in_sizes, int n_in,
                              void* d_out, int out_size, void* d_ws, size_t ws_size,
                              hipStream_t stream)
{
    const float* x   = (const float*)d_in[0];
    const float* ex  = (const float*)d_in[1];
    const float* W   = (const float*)d_in[2];
    const float* A   = (const float*)d_in[3];
    const float* tgt = (const float*)d_in[4];

    float* out0 = (float*)d_out;
    float* out1 = out0 + (size_t)BATCH * DIM;
    float* out2 = out1 + (size_t)BATCH * DIM;

    unsigned short* sigb = (unsigned short*)d_ws;                                   // 16 MiB
    unsigned short* Abf  = (unsigned short*)((char*)d_ws + (size_t)16 * 1024 * 1024); // 2 MiB

    prep_kernel<<<4608, 256, 0, stream>>>(x, A, sigb, Abf, out2);
    gemm_kernel<<<(BATCH / BM) * (DIM / BN), 512, 0, stream>>>(
        x, ex, W, tgt, sigb, Abf, out0, out1);
}